// Round 9
// baseline (1064.303 us; speedup 1.0000x reference)
//
#include <hip/hip_runtime.h>

#define MDIM 8192
#define NDIM 16384
#define KDIM 4096

typedef __bf16 bf16x8 __attribute__((ext_vector_type(8)));
typedef float f32x4 __attribute__((ext_vector_type(4)));
typedef float f32x16 __attribute__((ext_vector_type(16)));

__device__ __forceinline__ unsigned short f2bf(float f) {
  __bf16 h = (__bf16)f;
  return __builtin_bit_cast(unsigned short, h);
}

__device__ __forceinline__ void gload_lds16(const void* g, void* l) {
  __builtin_amdgcn_global_load_lds(
      (const __attribute__((address_space(1))) unsigned int*)g,
      (__attribute__((address_space(3))) unsigned int*)l, 16, 0, 0);
}

// ======== ws layouts (ks-plane-major; all GEMM LDS traffic contiguous) ======
// Ab: [mtile(32)][kt64(64)][ks(8)][row(256)][8]   piece (kq) = ks 4q..4q+3 = 16KB
// Wb: [ntile(64)][kt64(64)][ks(8)][row(256)][8]
// (ks = k/8 within the BK=64 tile; cell = 8 bf16 = 16B)

// ---------- pass 1a: fp32 -> bf16 into Ab (LDS-bounced transpose) ----------
__global__ __launch_bounds__(256) void cvt_a_kernel(const float* __restrict__ a,
                                                    unsigned short* __restrict__ o) {
  __shared__ unsigned short lds[4 * 2056];  // 4 ks-planes, +8 pad each
  const int mt = blockIdx.x >> 7;           // 0..31
  const int kt = (blockIdx.x >> 1) & 63;    // 0..63
  const int kq = blockIdx.x & 1;            // 0..1
  const int tid = threadIdx.x;
#pragma unroll
  for (int j = 0; j < 8; ++j) {
    const int idx = tid + j * 256;          // 0..2047
    const int row = idx >> 3;               // 0..255
    const int kc = idx & 7;                 // float4-chunk in row (32 k)
    float4 v = *(const float4*)(a + (long long)(mt * 256 + row) * KDIM +
                                kt * 64 + kq * 32 + kc * 4);
    ushort4 u;
    u.x = f2bf(v.x); u.y = f2bf(v.y); u.z = f2bf(v.z); u.w = f2bf(v.w);
    *(ushort4*)&lds[(kc >> 1) * 2056 + row * 8 + (kc & 1) * 4] = u;
  }
  __syncthreads();
  unsigned short* dst = o + (((long long)mt * 64 + kt) << 14) + (kq << 13);
#pragma unroll
  for (int j = 0; j < 4; ++j) {
    const int c = tid + j * 256;            // 0..1023 cells
    *(uint4*)(dst + c * 8) = *(const uint4*)&lds[(c >> 8) * 2056 + (c & 255) * 8];
  }
}

// ---------- pass 1b: int32 (int8 values) -> bf16 into Wb ----------
__global__ __launch_bounds__(256) void cvt_w_kernel(const int* __restrict__ w,
                                                    unsigned short* __restrict__ o) {
  __shared__ unsigned short lds[4 * 2056];
  const int nt = blockIdx.x >> 7;           // 0..63
  const int kt = (blockIdx.x >> 1) & 63;
  const int kq = blockIdx.x & 1;
  const int tid = threadIdx.x;
#pragma unroll
  for (int j = 0; j < 8; ++j) {
    const int idx = tid + j * 256;
    const int row = idx >> 3;
    const int kc = idx & 7;
    int4 v = *(const int4*)(w + (long long)(nt * 256 + row) * KDIM +
                            kt * 64 + kq * 32 + kc * 4);
    ushort4 u;
    u.x = f2bf((float)v.x); u.y = f2bf((float)v.y);
    u.z = f2bf((float)v.z); u.w = f2bf((float)v.w);
    *(ushort4*)&lds[(kc >> 1) * 2056 + row * 8 + (kc & 1) * 4] = u;
  }
  __syncthreads();
  unsigned short* dst = o + (((long long)nt * 64 + kt) << 14) + (kq << 13);
#pragma unroll
  for (int j = 0; j < 4; ++j) {
    const int c = tid + j * 256;
    *(uint4*)(dst + c * 8) = *(const uint4*)&lds[(c >> 8) * 2056 + (c & 255) * 8];
  }
}

// ---------- pass 2: v8 structure, deepened gates (vmcnt(8) x2 per tile) ------
// Buf (64KB): A = [ks(8)][row(256)][16B] at +0; B = same at +32768.
// Issue order (4 loads/piece): ..., kq1(t) [t-1.A], kq0(t+1) [t-1.B],
//   kq1(t+1) [t.A], kq0(t+2) [t.B], ...
// Phase A reads planes 0-3 (kq0) only; phase B reads planes 4-7 (kq1) only.
// A-end gate: need kq1(t) retired -> 8 younger outstanding -> vmcnt(8).
// B-end gate: need kq0(t+1) retired -> 8 younger outstanding -> vmcnt(8).
// Both are no-ops when on time: each piece gets ~1 full tile of flight.
// Tail: A-end t=63 -> vmcnt(0); B-end t=62 -> vmcnt(4), t=63 -> none.
__global__ __launch_bounds__(512, 2) void gemm_bf16_v9(
    const unsigned short* __restrict__ Ab, const unsigned short* __restrict__ Wb,
    const float* __restrict__ sc, const float* __restrict__ bi,
    float* __restrict__ out) {
  __shared__ alignas(16) char sm[2 * 65536];
  const int tid = threadIdx.x;
  const int lane = tid & 63;
  const int wv = tid >> 6;
  const int l31 = lane & 31;
  const int l32 = lane >> 5;
  const int wr = wv >> 2;   // 0..1 -> rows wr*128
  const int wc = wv & 3;    // 0..3 -> cols wc*64
  // 2D XCD chunking (verified: FETCH ~0.8 GB)
  const int c = blockIdx.x & 7;
  const int l = blockIdx.x >> 3;              // 0..255
  const int mA = ((c & 3) << 3) + (l & 7);    // 0..31
  const int nT = ((c >> 2) << 5) + (l >> 3);  // 0..63
  const int bm = mA << 8;
  const int bn = nT << 8;

  // frag byte-offsets (tile-invariant); each read = 32 lanes x 16B contiguous
  int aOff[4][4], bOff[4][2];
#pragma unroll
  for (int kk = 0; kk < 4; ++kk) {
#pragma unroll
    for (int mb = 0; mb < 4; ++mb)
      aOff[kk][mb] = (kk * 2 + l32) * 4096 + (wr * 128 + mb * 32 + l31) * 16;
#pragma unroll
    for (int nb = 0; nb < 2; ++nb)
      bOff[kk][nb] = 32768 + (kk * 2 + l32) * 4096 + (wc * 64 + nb * 32 + l31) * 16;
  }

  f32x16 acc[4][2] = {};

  const unsigned short* a0 = Ab + (((long long)mA * 64) << 14) + (tid << 3);
  const unsigned short* b0 = Wb + (((long long)nT * 64) << 14) + (tid << 3);
  const int t16 = tid << 4;

  // prologue: kq0(0), kq1(0), kq0(1) = 12 loads; gate kq0(0) -> vmcnt(8)
  gload_lds16(a0, sm + t16);
  gload_lds16(a0 + 4096, sm + 8192 + t16);
  gload_lds16(b0, sm + 32768 + t16);
  gload_lds16(b0 + 4096, sm + 40960 + t16);
  gload_lds16(a0 + 8192, sm + 16384 + t16);
  gload_lds16(a0 + 12288, sm + 24576 + t16);
  gload_lds16(b0 + 8192, sm + 49152 + t16);
  gload_lds16(b0 + 12288, sm + 57344 + t16);
  gload_lds16(a0 + 16384, sm + 65536 + t16);
  gload_lds16(a0 + 20480, sm + 65536 + 8192 + t16);
  gload_lds16(b0 + 16384, sm + 65536 + 32768 + t16);
  gload_lds16(b0 + 20480, sm + 65536 + 40960 + t16);
  asm volatile("s_waitcnt vmcnt(8)" ::: "memory");
  __builtin_amdgcn_s_barrier();

  const unsigned short* pAq1 = a0 + 16384 + 8192;  // kq1 of tile 1
  const unsigned short* pBq1 = b0 + 16384 + 8192;
  const unsigned short* pAq0 = a0 + 32768;         // kq0 of tile 2
  const unsigned short* pBq0 = b0 + 32768;

  auto PHASE = [&](const char* cur, const int kkA, const int kkB) {
    bf16x8 aF0[4], aF1[4], bF0[2], bF1[2];
#pragma unroll
    for (int mb = 0; mb < 4; ++mb) aF0[mb] = *(const bf16x8*)(cur + aOff[kkA][mb]);
#pragma unroll
    for (int nb = 0; nb < 2; ++nb) bF0[nb] = *(const bf16x8*)(cur + bOff[kkA][nb]);
#pragma unroll
    for (int mb = 0; mb < 4; ++mb) aF1[mb] = *(const bf16x8*)(cur + aOff[kkB][mb]);
#pragma unroll
    for (int nb = 0; nb < 2; ++nb) bF1[nb] = *(const bf16x8*)(cur + bOff[kkB][nb]);
#pragma unroll
    for (int mb = 0; mb < 4; ++mb)
#pragma unroll
      for (int nb = 0; nb < 2; ++nb)
        acc[mb][nb] = __builtin_amdgcn_mfma_f32_32x32x16_bf16(
            aF0[mb], bF0[nb], acc[mb][nb], 0, 0, 0);
#pragma unroll
    for (int mb = 0; mb < 4; ++mb)
#pragma unroll
      for (int nb = 0; nb < 2; ++nb)
        acc[mb][nb] = __builtin_amdgcn_mfma_f32_32x32x16_bf16(
            aF1[mb], bF1[nb], acc[mb][nb], 0, 0, 0);
  };

  auto TILE = [&](int t, char* cur, char* obuf) {
    // ---- phase A: stage kq1(t+1) -> obuf planes 4-7; compute kk 0,1 ----
    if (t + 1 < 64) {
      gload_lds16(pAq1, obuf + 16384 + t16);
      gload_lds16(pAq1 + 4096, obuf + 24576 + t16);
      gload_lds16(pBq1, obuf + 49152 + t16);
      gload_lds16(pBq1 + 4096, obuf + 57344 + t16);
    }
    __builtin_amdgcn_s_setprio(1);
    PHASE(cur, 0, 1);
    __builtin_amdgcn_s_setprio(0);
    if (t < 63) {
      asm volatile("s_waitcnt vmcnt(8)" ::: "memory");  // kq1(t) resident
    } else {
      asm volatile("s_waitcnt vmcnt(0)" ::: "memory");
    }
    __builtin_amdgcn_s_barrier();
    // ---- phase B: stage kq0(t+2) -> cur planes 0-3; compute kk 2,3 ----
    if (t + 2 < 64) {
      gload_lds16(pAq0, cur + t16);
      gload_lds16(pAq0 + 4096, cur + 8192 + t16);
      gload_lds16(pBq0, cur + 32768 + t16);
      gload_lds16(pBq0 + 4096, cur + 40960 + t16);
    }
    __builtin_amdgcn_s_setprio(1);
    PHASE(cur, 2, 3);
    __builtin_amdgcn_s_setprio(0);
    if (t <= 61) {
      asm volatile("s_waitcnt vmcnt(8)" ::: "memory");  // kq0(t+1) resident
    } else if (t == 62) {
      asm volatile("s_waitcnt vmcnt(4)" ::: "memory");
    }
    if (t < 63) __builtin_amdgcn_s_barrier();
    pAq1 += 16384; pBq1 += 16384; pAq0 += 16384; pBq0 += 16384;
  };

  for (int t = 0; t < 64; t += 2) {
    TILE(t, sm, sm + 65536);
    TILE(t + 1, sm + 65536, sm);
  }

  // epilogue: 32x32 C/D layout col = lane&31, row = (r&3) + 8*(r>>2) + 4*l32
  float sv[2], bv[2];
#pragma unroll
  for (int nb = 0; nb < 2; ++nb) {
    const int cc = bn + wc * 64 + nb * 32 + l31;
    sv[nb] = sc[cc];
    bv[nb] = bi[cc];
  }
#pragma unroll
  for (int mb = 0; mb < 4; ++mb) {
    const int rb = bm + wr * 128 + mb * 32 + l32 * 4;
#pragma unroll
    for (int nb = 0; nb < 2; ++nb) {
      const int cc = bn + wc * 64 + nb * 32 + l31;
      const float s = sv[nb], b = bv[nb];
#pragma unroll
      for (int r = 0; r < 16; ++r) {
        const long long row = rb + (r & 3) + 8 * (r >> 2);
        __builtin_nontemporal_store(acc[mb][nb][r] * s + b, out + row * NDIM + cc);
      }
    }
  }
}

// ---------- fallback: inline-convert reg-staged GEMM (if ws too small) ----------
__global__ __launch_bounds__(256, 2) void gemm_inline(
    const float* __restrict__ A, const int* __restrict__ W,
    const float* __restrict__ sc, const float* __restrict__ bi,
    float* __restrict__ out) {
  __shared__ unsigned short As[128 * 72];
  __shared__ unsigned short Bs[128 * 72];
  const int tid = threadIdx.x;
  const int lane = tid & 63;
  const int wv = tid >> 6;
  const int wg = (blockIdx.x & 7) * 1024 + (blockIdx.x >> 3);
  const int bm = (wg & 63) * 128;
  const int bn = (wg >> 6) * 128;
  const int wr = (wv >> 1) * 64;
  const int wc = (wv & 1) * 64;
  const int r16 = lane & 15;
  const int g4 = lane >> 4;

  f32x4 acc[4][4] = {};

  const int srow = tid >> 4;
  const int sc4 = (tid & 15) << 2;
  const float* aPtr = A + (long long)(bm + srow) * KDIM + sc4;
  const int* wPtr = W + (long long)(bn + srow) * KDIM + sc4;

  for (int kt = 0; kt < KDIM; kt += 64) {
    float4 av[8];
    int4 wv4[8];
#pragma unroll
    for (int j = 0; j < 8; ++j)
      av[j] = *(const float4*)(aPtr + (long long)j * 16 * KDIM + kt);
#pragma unroll
    for (int j = 0; j < 8; ++j)
      wv4[j] = *(const int4*)(wPtr + (long long)j * 16 * KDIM + kt);
    __syncthreads();
#pragma unroll
    for (int j = 0; j < 8; ++j) {
      ushort4 u;
      u.x = f2bf(av[j].x); u.y = f2bf(av[j].y);
      u.z = f2bf(av[j].z); u.w = f2bf(av[j].w);
      *(ushort4*)&As[(srow + j * 16) * 72 + sc4] = u;
    }
#pragma unroll
    for (int j = 0; j < 8; ++j) {
      ushort4 u;
      u.x = f2bf((float)wv4[j].x); u.y = f2bf((float)wv4[j].y);
      u.z = f2bf((float)wv4[j].z); u.w = f2bf((float)wv4[j].w);
      *(ushort4*)&Bs[(srow + j * 16) * 72 + sc4] = u;
    }
    __syncthreads();
#pragma unroll
    for (int ks = 0; ks < 2; ++ks) {
      bf16x8 aF[4], bF[4];
      const int kofs = ks * 32 + g4 * 8;
#pragma unroll
      for (int m2 = 0; m2 < 4; ++m2)
        aF[m2] = *(const bf16x8*)&As[(wr + m2 * 16 + r16) * 72 + kofs];
#pragma unroll
      for (int n2 = 0; n2 < 4; ++n2)
        bF[n2] = *(const bf16x8*)&Bs[(wc + n2 * 16 + r16) * 72 + kofs];
#pragma unroll
      for (int m2 = 0; m2 < 4; ++m2)
#pragma unroll
        for (int n2 = 0; n2 < 4; ++n2)
          acc[m2][n2] = __builtin_amdgcn_mfma_f32_16x16x32_bf16(
              aF[m2], bF[n2], acc[m2][n2], 0, 0, 0);
    }
  }

  float sv[4], bv[4];
#pragma unroll
  for (int n2 = 0; n2 < 4; ++n2) {
    const int c = bn + wc + n2 * 16 + r16;
    sv[n2] = sc[c];
    bv[n2] = bi[c];
  }
#pragma unroll
  for (int m2 = 0; m2 < 4; ++m2) {
    const int row0 = bm + wr + m2 * 16 + g4 * 4;
#pragma unroll
    for (int n2 = 0; n2 < 4; ++n2) {
      const int c = bn + wc + n2 * 16 + r16;
      float* op = out + (long long)row0 * NDIM + c;
#pragma unroll
      for (int r = 0; r < 4; ++r)
        op[(long long)r * NDIM] = acc[m2][n2][r] * sv[n2] + bv[n2];
    }
  }
}

extern "C" void kernel_launch(void* const* d_in, const int* in_sizes, int n_in,
                              void* d_out, int out_size, void* d_ws, size_t ws_size,
                              hipStream_t stream) {
  const float* A = (const float*)d_in[0];
  const int* W = (const int*)d_in[1];
  const float* sc = (const float*)d_in[2];
  const float* bi = (const float*)d_in[3];
  float* out = (float*)d_out;

  const long long nA = (long long)MDIM * KDIM;
  const long long nW = (long long)NDIM * KDIM;
  const size_t needA = (size_t)nA * sizeof(unsigned short);
  const size_t needW = (size_t)nW * sizeof(unsigned short);

  if (d_ws != nullptr && ws_size >= needA + needW) {
    unsigned short* Ab = (unsigned short*)d_ws;
    unsigned short* Wb = (unsigned short*)((char*)d_ws + needA);
    cvt_a_kernel<<<4096, 256, 0, stream>>>(A, Ab);
    cvt_w_kernel<<<8192, 256, 0, stream>>>(W, Wb);
    gemm_bf16_v9<<<2048, 512, 0, stream>>>(Ab, Wb, sc, bi, out);
  } else {
    gemm_inline<<<8192, 256, 0, stream>>>(A, W, sc, bi, out);
  }
}

// Round 11
// 1033.806 us; speedup vs baseline: 1.0295x; 1.0295x over previous
//
#include <hip/hip_runtime.h>

#define MDIM 8192
#define NDIM 16384
#define KDIM 4096

typedef __bf16 bf16x8 __attribute__((ext_vector_type(8)));
typedef float f32x4 __attribute__((ext_vector_type(4)));
typedef float f32x16 __attribute__((ext_vector_type(16)));

__device__ __forceinline__ unsigned short f2bf(float f) {
  __bf16 h = (__bf16)f;
  return __builtin_bit_cast(unsigned short, h);
}

__device__ __forceinline__ void gload_lds16(const void* g, void* l) {
  __builtin_amdgcn_global_load_lds(
      (const __attribute__((address_space(1))) unsigned int*)g,
      (__attribute__((address_space(3))) unsigned int*)l, 16, 0, 0);
}

// ======== ws layouts (ks-plane-major; all GEMM LDS traffic contiguous) ======
// Ab: [mtile(32)][kt64(64)][ks(8)][row(256)][8]   half-tile = 4 ks-planes = 16KB
// Wb: [ntile(64)][kt64(64)][ks(8)][row(256)][8]

// ---------- pass 1a: fp32 -> bf16 into Ab (LDS-bounced transpose) ----------
__global__ __launch_bounds__(256) void cvt_a_kernel(const float* __restrict__ a,
                                                    unsigned short* __restrict__ o) {
  __shared__ unsigned short lds[4 * 2056];
  const int mt = blockIdx.x >> 7;
  const int kt = (blockIdx.x >> 1) & 63;
  const int kq = blockIdx.x & 1;
  const int tid = threadIdx.x;
#pragma unroll
  for (int j = 0; j < 8; ++j) {
    const int idx = tid + j * 256;
    const int row = idx >> 3;
    const int kc = idx & 7;
    float4 v = *(const float4*)(a + (long long)(mt * 256 + row) * KDIM +
                                kt * 64 + kq * 32 + kc * 4);
    ushort4 u;
    u.x = f2bf(v.x); u.y = f2bf(v.y); u.z = f2bf(v.z); u.w = f2bf(v.w);
    *(ushort4*)&lds[(kc >> 1) * 2056 + row * 8 + (kc & 1) * 4] = u;
  }
  __syncthreads();
  unsigned short* dst = o + (((long long)mt * 64 + kt) << 14) + (kq << 13);
#pragma unroll
  for (int j = 0; j < 4; ++j) {
    const int c = tid + j * 256;
    *(uint4*)(dst + c * 8) = *(const uint4*)&lds[(c >> 8) * 2056 + (c & 255) * 8];
  }
}

// ---------- pass 1b: int32 (int8 values) -> bf16 into Wb ----------
__global__ __launch_bounds__(256) void cvt_w_kernel(const int* __restrict__ w,
                                                    unsigned short* __restrict__ o) {
  __shared__ unsigned short lds[4 * 2056];
  const int nt = blockIdx.x >> 7;
  const int kt = (blockIdx.x >> 1) & 63;
  const int kq = blockIdx.x & 1;
  const int tid = threadIdx.x;
#pragma unroll
  for (int j = 0; j < 8; ++j) {
    const int idx = tid + j * 256;
    const int row = idx >> 3;
    const int kc = idx & 7;
    int4 v = *(const int4*)(w + (long long)(nt * 256 + row) * KDIM +
                            kt * 64 + kq * 32 + kc * 4);
    ushort4 u;
    u.x = f2bf((float)v.x); u.y = f2bf((float)v.y);
    u.z = f2bf((float)v.z); u.w = f2bf((float)v.w);
    *(ushort4*)&lds[(kc >> 1) * 2056 + row * 8 + (kc & 1) * 4] = u;
  }
  __syncthreads();
  unsigned short* dst = o + (((long long)nt * 64 + kt) << 14) + (kq << 13);
#pragma unroll
  for (int j = 0; j < 4; ++j) {
    const int c = tid + j * 256;
    *(uint4*)(dst + c * 8) = *(const uint4*)&lds[(c >> 8) * 2056 + (c & 255) * 8];
  }
}

// ---------- pass 2: 256x256, 128 half-tile phases, reg-frag double-buffer ----
// LDS: 4 slots x 32KB (A 16KB + B 16KB). Phase ph:
//   ds_read 12 frags(ph+1) -> other bank | stage half(ph+3) | MFMA bank(ph)
//   | vmcnt(4) [retires half ph+2; only half ph+3 stays in flight] | barrier
// Residency ledger: at START of phase ph (post ph-1 gate+barrier) halves
// <= ph+1 are retired -> early LOADF(ph+1) is race-free. Prologue gate must
// therefore retire halves 0 AND 1: vmcnt(4) (v10 bug: vmcnt(8) left half 1
// in flight -> phase-0 read race -> absmax 44.6).
__global__ __launch_bounds__(512, 2) void gemm_bf16_v11(
    const unsigned short* __restrict__ Ab, const unsigned short* __restrict__ Wb,
    const float* __restrict__ sc, const float* __restrict__ bi,
    float* __restrict__ out) {
  __shared__ alignas(16) char sm[4 * 32768];
  const int tid = threadIdx.x;
  const int lane = tid & 63;
  const int wv = tid >> 6;
  const int l31 = lane & 31;
  const int l32 = lane >> 5;
  const int wr = wv >> 2;
  const int wc = wv & 3;
  // 2D XCD chunking (verified: FETCH ~0.8 GB)
  const int c = blockIdx.x & 7;
  const int l = blockIdx.x >> 3;
  const int mA = ((c & 3) << 3) + (l & 7);
  const int nT = ((c >> 2) << 5) + (l >> 3);
  const int bm = mA << 8;
  const int bn = nT << 8;

  // slot-relative frag byte-offsets; each read = 32 lanes x 16B contiguous
  int aO[8], bO[4];
#pragma unroll
  for (int kk = 0; kk < 2; ++kk) {
#pragma unroll
    for (int mb = 0; mb < 4; ++mb)
      aO[kk * 4 + mb] = (kk * 2 + l32) * 4096 + (wr * 128 + mb * 32 + l31) * 16;
#pragma unroll
    for (int nb = 0; nb < 2; ++nb)
      bO[kk * 2 + nb] =
          16384 + (kk * 2 + l32) * 4096 + (wc * 64 + nb * 32 + l31) * 16;
  }

  f32x16 acc[4][2] = {};

  const unsigned short* a0 = Ab + (((long long)mA * 64) << 14) + (tid << 3);
  const unsigned short* b0 = Wb + (((long long)nT * 64) << 14) + (tid << 3);
  const int t16 = tid << 4;
  char* const S0 = sm;
  char* const S1 = sm + 32768;
  char* const S2 = sm + 65536;
  char* const S3 = sm + 98304;

  const unsigned short* pA = a0;  // next half to stage (advances 8192/stage)
  const unsigned short* pB = b0;

  auto STAGE = [&](char* slot) {
    gload_lds16(pA, slot + t16);
    gload_lds16(pA + 4096, slot + 8192 + t16);
    gload_lds16(pB, slot + 16384 + t16);
    gload_lds16(pB + 4096, slot + 24576 + t16);
    pA += 8192;
    pB += 8192;
  };
  auto LOADF = [&](const char* slot, bf16x8* aF, bf16x8* bF) {
#pragma unroll
    for (int i = 0; i < 8; ++i) aF[i] = *(const bf16x8*)(slot + aO[i]);
#pragma unroll
    for (int i = 0; i < 4; ++i) bF[i] = *(const bf16x8*)(slot + bO[i]);
  };
  auto MFMAS = [&](const bf16x8* aF, const bf16x8* bF) {
    __builtin_amdgcn_s_setprio(1);
#pragma unroll
    for (int kk = 0; kk < 2; ++kk)
#pragma unroll
      for (int mb = 0; mb < 4; ++mb)
#pragma unroll
        for (int nb = 0; nb < 2; ++nb)
          acc[mb][nb] = __builtin_amdgcn_mfma_f32_32x32x16_bf16(
              aF[kk * 4 + mb], bF[kk * 2 + nb], acc[mb][nb], 0, 0, 0);
    __builtin_amdgcn_s_setprio(0);
  };

  bf16x8 aFa[8], bFa[4], aFb[8], bFb[4];

  // prologue: stage halves 0,1,2 -> S0,S1,S2; retire halves 0,1 (vmcnt(4):
  // only half 2's 4 loads stay in flight); preload bank a from half 0.
  STAGE(S0);
  STAGE(S1);
  STAGE(S2);
  asm volatile("s_waitcnt vmcnt(4)" ::: "memory");
  __builtin_amdgcn_s_barrier();
  LOADF(S0, aFa, bFa);

#define PH(rdSlot, stSlot, aCur, bCur, aNxt, bNxt)        \
  LOADF(rdSlot, aNxt, bNxt);                              \
  STAGE(stSlot);                                          \
  MFMAS(aCur, bCur);                                      \
  asm volatile("s_waitcnt vmcnt(4)" ::: "memory");        \
  __builtin_amdgcn_s_barrier();

  for (int i = 0; i < 30; ++i) {  // phases 0..119
    PH(S1, S3, aFa, bFa, aFb, bFb)
    PH(S2, S0, aFb, bFb, aFa, bFa)
    PH(S3, S1, aFa, bFa, aFb, bFb)
    PH(S0, S2, aFb, bFb, aFa, bFa)
  }
  // tail: phases 120..127
  PH(S1, S3, aFa, bFa, aFb, bFb)  // 120 (stage half 123)
  PH(S2, S0, aFb, bFb, aFa, bFa)  // 121 (stage half 124)
  PH(S3, S1, aFa, bFa, aFb, bFb)  // 122 (stage half 125)
  PH(S0, S2, aFb, bFb, aFa, bFa)  // 123 (stage half 126)
  PH(S1, S3, aFa, bFa, aFb, bFb)  // 124 (stage half 127)
#undef PH
  // 125: read S2 (half 126); no stage; gate vmcnt(0) [retires half 127]
  LOADF(S2, aFa, bFa);
  MFMAS(aFb, bFb);
  asm volatile("s_waitcnt vmcnt(0)" ::: "memory");
  __builtin_amdgcn_s_barrier();
  // 126: read S3 (half 127); no stage; no gate
  LOADF(S3, aFb, bFb);
  MFMAS(aFa, bFa);
  __builtin_amdgcn_s_barrier();
  // 127: MFMA only
  MFMAS(aFb, bFb);

  // epilogue: 32x32 C/D layout col = lane&31, row = (r&3) + 8*(r>>2) + 4*l32
  float sv[2], bv[2];
#pragma unroll
  for (int nb = 0; nb < 2; ++nb) {
    const int cc = bn + wc * 64 + nb * 32 + l31;
    sv[nb] = sc[cc];
    bv[nb] = bi[cc];
  }
#pragma unroll
  for (int mb = 0; mb < 4; ++mb) {
    const int rb = bm + wr * 128 + mb * 32 + l32 * 4;
#pragma unroll
    for (int nb = 0; nb < 2; ++nb) {
      const int cc = bn + wc * 64 + nb * 32 + l31;
      const float s = sv[nb], b = bv[nb];
#pragma unroll
      for (int r = 0; r < 16; ++r) {
        const long long row = rb + (r & 3) + 8 * (r >> 2);
        __builtin_nontemporal_store(acc[mb][nb][r] * s + b, out + row * NDIM + cc);
      }
    }
  }
}

// ---------- fallback: inline-convert reg-staged GEMM (if ws too small) ----------
__global__ __launch_bounds__(256, 2) void gemm_inline(
    const float* __restrict__ A, const int* __restrict__ W,
    const float* __restrict__ sc, const float* __restrict__ bi,
    float* __restrict__ out) {
  __shared__ unsigned short As[128 * 72];
  __shared__ unsigned short Bs[128 * 72];
  const int tid = threadIdx.x;
  const int lane = tid & 63;
  const int wv = tid >> 6;
  const int wg = (blockIdx.x & 7) * 1024 + (blockIdx.x >> 3);
  const int bm = (wg & 63) * 128;
  const int bn = (wg >> 6) * 128;
  const int wr = (wv >> 1) * 64;
  const int wc = (wv & 1) * 64;
  const int r16 = lane & 15;
  const int g4 = lane >> 4;

  f32x4 acc[4][4] = {};

  const int srow = tid >> 4;
  const int sc4 = (tid & 15) << 2;
  const float* aPtr = A + (long long)(bm + srow) * KDIM + sc4;
  const int* wPtr = W + (long long)(bn + srow) * KDIM + sc4;

  for (int kt = 0; kt < KDIM; kt += 64) {
    float4 av[8];
    int4 wv4[8];
#pragma unroll
    for (int j = 0; j < 8; ++j)
      av[j] = *(const float4*)(aPtr + (long long)j * 16 * KDIM + kt);
#pragma unroll
    for (int j = 0; j < 8; ++j)
      wv4[j] = *(const int4*)(wPtr + (long long)j * 16 * KDIM + kt);
    __syncthreads();
#pragma unroll
    for (int j = 0; j < 8; ++j) {
      ushort4 u;
      u.x = f2bf(av[j].x); u.y = f2bf(av[j].y);
      u.z = f2bf(av[j].z); u.w = f2bf(av[j].w);
      *(ushort4*)&As[(srow + j * 16) * 72 + sc4] = u;
    }
#pragma unroll
    for (int j = 0; j < 8; ++j) {
      ushort4 u;
      u.x = f2bf((float)wv4[j].x); u.y = f2bf((float)wv4[j].y);
      u.z = f2bf((float)wv4[j].z); u.w = f2bf((float)wv4[j].w);
      *(ushort4*)&Bs[(srow + j * 16) * 72 + sc4] = u;
    }
    __syncthreads();
#pragma unroll
    for (int ks = 0; ks < 2; ++ks) {
      bf16x8 aF[4], bF[4];
      const int kofs = ks * 32 + g4 * 8;
#pragma unroll
      for (int m2 = 0; m2 < 4; ++m2)
        aF[m2] = *(const bf16x8*)&As[(wr + m2 * 16 + r16) * 72 + kofs];
#pragma unroll
      for (int n2 = 0; n2 < 4; ++n2)
        bF[n2] = *(const bf16x8*)&Bs[(wc + n2 * 16 + r16) * 72 + kofs];
#pragma unroll
      for (int m2 = 0; m2 < 4; ++m2)
#pragma unroll
        for (int n2 = 0; n2 < 4; ++n2)
          acc[m2][n2] = __builtin_amdgcn_mfma_f32_16x16x32_bf16(
              aF[m2], bF[n2], acc[m2][n2], 0, 0, 0);
    }
  }

  float sv[4], bv[4];
#pragma unroll
  for (int n2 = 0; n2 < 4; ++n2) {
    const int c = bn + wc + n2 * 16 + r16;
    sv[n2] = sc[c];
    bv[n2] = bi[c];
  }
#pragma unroll
  for (int m2 = 0; m2 < 4; ++m2) {
    const int row0 = bm + wr + m2 * 16 + g4 * 4;
#pragma unroll
    for (int n2 = 0; n2 < 4; ++n2) {
      const int c = bn + wc + n2 * 16 + r16;
      float* op = out + (long long)row0 * NDIM + c;
#pragma unroll
      for (int r = 0; r < 4; ++r)
        op[(long long)r * NDIM] = acc[m2][n2][r] * sv[n2] + bv[n2];
    }
  }
}

extern "C" void kernel_launch(void* const* d_in, const int* in_sizes, int n_in,
                              void* d_out, int out_size, void* d_ws, size_t ws_size,
                              hipStream_t stream) {
  const float* A = (const float*)d_in[0];
  const int* W = (const int*)d_in[1];
  const float* sc = (const float*)d_in[2];
  const float* bi = (const float*)d_in[3];
  float* out = (float*)d_out;

  const long long nA = (long long)MDIM * KDIM;
  const long long nW = (long long)NDIM * KDIM;
  const size_t needA = (size_t)nA * sizeof(unsigned short);
  const size_t needW = (size_t)nW * sizeof(unsigned short);

  if (d_ws != nullptr && ws_size >= needA + needW) {
    unsigned short* Ab = (unsigned short*)d_ws;
    unsigned short* Wb = (unsigned short*)((char*)d_ws + needA);
    cvt_a_kernel<<<4096, 256, 0, stream>>>(A, Ab);
    cvt_w_kernel<<<8192, 256, 0, stream>>>(W, Wb);
    gemm_bf16_v11<<<2048, 512, 0, stream>>>(Ab, Wb, sc, bi, out);
  } else {
    gemm_inline<<<8192, 256, 0, stream>>>(A, W, sc, bi, out);
  }
}